// Round 1
// baseline (395.054 us; speedup 1.0000x reference)
//
#include <hip/hip_runtime.h>
#include <math.h>

// MAPLoss: loss = mean_{b,m,n}[ 0.5*T^t Sy^{-1} T + 0.5*log(clip(det Sy, EPS)) ]
//          zeroed if max(t1) > 1e7.
// B=16, C=3, M=N=512. target/mu: [B,C,M,N]; sigma_y: [B,M,N,3,3].
// sigma_mu (d_in[2]) and sigma_n (d_in[3]) are unused by the math.

#define EPS_F 1e-06f
#define T1_CLIP_F 1e7f

constexpr int Bc = 16, Mc = 512, Nc = 512;
constexpr long long MN = (long long)Mc * Nc;      // 262144 = 2^18
constexpr long long P  = (long long)Bc * MN;      // 4194304
constexpr int NBLK = 2048;
constexpr int TPB  = 256;

__global__ __launch_bounds__(TPB) void map_partial(
    const float* __restrict__ target, const float* __restrict__ mu,
    const float* __restrict__ sigma, double* __restrict__ psum,
    float* __restrict__ pmax)
{
    double acc = 0.0;
    float mx = 0.0f;   // t1 >= 0 (Sy is SPD), so 0 is a safe identity
    const long long tid    = (long long)blockIdx.x * blockDim.x + threadIdx.x;
    const long long stride = (long long)gridDim.x * blockDim.x;

    for (long long p = tid; p < P; p += stride) {
        const long long b = p >> 18;           // p / MN
        const long long r = p & (MN - 1);      // p % MN
        const long long tb = b * (3 * MN) + r;

        const float t0 = target[tb]          - mu[tb];
        const float t1 = target[tb + MN]     - mu[tb + MN];
        const float t2 = target[tb + 2*MN]   - mu[tb + 2*MN];

        const float* s = sigma + 9 * p;
        const float s00 = s[0], s01 = s[1], s02 = s[2];
        const float s10 = s[3], s11 = s[4], s12 = s[5];
        const float s20 = s[6], s21 = s[7], s22 = s[8];

        // cofactors along first row -> det
        const float c00 = s11*s22 - s12*s21;
        const float c01 = s12*s20 - s10*s22;
        const float c02 = s10*s21 - s11*s20;
        const float det = s00*c00 + s01*c01 + s02*c02;

        // adjugate (det * inverse)
        const float a00 = c00;
        const float a01 = s02*s21 - s01*s22;
        const float a02 = s01*s12 - s02*s11;
        const float a10 = c01;
        const float a11 = s00*s22 - s02*s20;
        const float a12 = s02*s10 - s00*s12;
        const float a20 = c02;
        const float a21 = s01*s20 - s00*s21;
        const float a22 = s00*s11 - s01*s10;

        const float q = t0*(a00*t0 + a01*t1 + a02*t2)
                      + t1*(a10*t0 + a11*t1 + a12*t2)
                      + t2*(a20*t0 + a21*t1 + a22*t2);

        const float t1v  = 0.5f * q / det;
        const float dets = 0.5f * logf(fmaxf(det, EPS_F));

        acc += (double)(t1v + dets);
        mx = fmaxf(mx, t1v);
    }

    // wave-64 shuffle reduce
    for (int off = 32; off > 0; off >>= 1) {
        acc += __shfl_down(acc, off, 64);
        mx = fmaxf(mx, __shfl_down(mx, off, 64));
    }
    __shared__ double ssum[TPB / 64];
    __shared__ float  smax[TPB / 64];
    const int lane = threadIdx.x & 63;
    const int wv   = threadIdx.x >> 6;
    if (lane == 0) { ssum[wv] = acc; smax[wv] = mx; }
    __syncthreads();
    if (threadIdx.x == 0) {
        double a = ssum[0] + ssum[1] + ssum[2] + ssum[3];
        float  m = fmaxf(fmaxf(smax[0], smax[1]), fmaxf(smax[2], smax[3]));
        psum[blockIdx.x] = a;
        pmax[blockIdx.x] = m;
    }
}

__global__ __launch_bounds__(TPB) void map_final(
    const double* __restrict__ psum, const float* __restrict__ pmax,
    float* __restrict__ out)
{
    double acc = 0.0;
    float mx = 0.0f;
    for (int i = threadIdx.x; i < NBLK; i += TPB) {
        acc += psum[i];
        mx = fmaxf(mx, pmax[i]);
    }
    for (int off = 32; off > 0; off >>= 1) {
        acc += __shfl_down(acc, off, 64);
        mx = fmaxf(mx, __shfl_down(mx, off, 64));
    }
    __shared__ double ssum[TPB / 64];
    __shared__ float  smax[TPB / 64];
    const int lane = threadIdx.x & 63;
    const int wv   = threadIdx.x >> 6;
    if (lane == 0) { ssum[wv] = acc; smax[wv] = mx; }
    __syncthreads();
    if (threadIdx.x == 0) {
        double a = ssum[0] + ssum[1] + ssum[2] + ssum[3];
        float  m = fmaxf(fmaxf(smax[0], smax[1]), fmaxf(smax[2], smax[3]));
        float loss = (float)(a / (double)P);
        out[0] = (m > T1_CLIP_F) ? 0.0f : loss;
    }
}

extern "C" void kernel_launch(void* const* d_in, const int* in_sizes, int n_in,
                              void* d_out, int out_size, void* d_ws, size_t ws_size,
                              hipStream_t stream) {
    const float* target  = (const float*)d_in[0];
    const float* mu      = (const float*)d_in[1];
    // d_in[2] = sigma_mu, d_in[3] = sigma_n : unused by the reference math
    const float* sigma_y = (const float*)d_in[4];

    double* psum = (double*)d_ws;                        // NBLK doubles
    float*  pmax = (float*)((char*)d_ws + NBLK * sizeof(double)); // NBLK floats

    map_partial<<<NBLK, TPB, 0, stream>>>(target, mu, sigma_y, psum, pmax);
    map_final<<<1, TPB, 0, stream>>>(psum, pmax, (float*)d_out);
}